// Round 8
// baseline (1627.958 us; speedup 1.0000x reference)
//
#include <hip/hip_runtime.h>

// ResidualNetwork forward, fp32, MI355X (gfx950).
// Round 8: weight delivery via the VMEM pipe. Duplicated (w,w) float2 stream
// (exact use order, same numerics as r3/r4/r6) read through a pointer offset
// by an OPAQUE VGPR zero (inline asm) -> compiler cannot prove uniformity ->
// emits per-lane global_load_dwordx4 (all lanes same addr = 1 L1 line,
// broadcast; stream is 27.8KB, L1-resident). Operands land directly in the
// VGPRs pk_fma reads; biases land directly in accumulators. Zero VALU cost
// per weight. VALU stream ~ pure v_pk_fma_f32 + pk_max.
// Ledger: r3/r6 scalar path = ~2cyc VALU tax per weight-pair (v_mov);
// r7 SGPR-pair pk operand = same tax inside the pk (6cyc); r4 LDS = DS pipe
// saturates per-CU. VMEM is the only idle pipe that can carry the weights.
// Predicted: VALU/wave = 12,960 pk + 920 relu + ~400 misc = 14.3k cyc;
// x32 wave-slots/SIMD = 458k cyc ~ 191us + idle -> 200-225us target.

#define NPTS 4194304
#define H 10
#define L 10

#define L1_OFF 40
#define BLK_OFF 150
#define BLK_STRIDE 320
#define L8_OFF 3350
#define L9_OFF 3460
#define NENT 3472

typedef float v2f __attribute__((ext_vector_type(2)));
typedef float v4f __attribute__((ext_vector_type(4)));

__device__ __forceinline__ v2f tov2(float2 w) { v2f r; r.x = w.x; r.y = w.y; return r; }
__device__ __forceinline__ v2f bc(float s) { v2f r; r.x = s; r.y = s; return r; }
__device__ __forceinline__ v2f fma2v(v2f a, v2f w, v2f c) {
    return __builtin_elementwise_fma(a, w, c);
}
__device__ __forceinline__ v2f relu2(v2f a) {
    return __builtin_elementwise_max(a, bc(0.0f));
}

// ---------------- prepack: weights -> use-order duplicated (w,w) pairs -------
__global__ __launch_bounds__(256) void prepack(
    const float* __restrict__ w0, const float* __restrict__ b0,
    const float* __restrict__ w1, const float* __restrict__ b1,
    const float* __restrict__ Wr1, const float* __restrict__ Br1,
    const float* __restrict__ Wr2, const float* __restrict__ Br2,
    const float* __restrict__ Wr3, const float* __restrict__ Br3,
    const float* __restrict__ w8, const float* __restrict__ b8,
    const float* __restrict__ w9, const float* __restrict__ b9,
    float2* __restrict__ wp)
{
    for (int idx = threadIdx.x; idx < NENT; idx += 256) {
        float v;
        if (idx < L1_OFF) {                       // layer0 per j: b, w0[0][j], w0[1][j], w0[2][j]
            int j = idx >> 2, r = idx & 3;
            v = (r == 0) ? b0[j] : w0[(r - 1) * H + j];
        } else if (idx < BLK_OFF) {               // layer1: b1[10], w1[100]
            int e = idx - L1_OFF;
            v = (e < H) ? b1[e] : w1[e - H];
        } else if (idx < L8_OFF) {                // blocks: B1, W1, B2+B3, W2, W3
            int e = idx - BLK_OFF;
            int l = e / BLK_STRIDE, m = e % BLK_STRIDE;
            if      (m < 10)  v = Br1[l * H + m];
            else if (m < 110) v = Wr1[l * H * H + (m - 10)];
            else if (m < 120) v = Br2[l * H + (m - 110)] + Br3[l * H + (m - 110)];
            else if (m < 220) v = Wr2[l * H * H + (m - 120)];
            else              v = Wr3[l * H * H + (m - 220)];
        } else if (idx < L9_OFF) {                // layer8: b8[10], w8[100]
            int e = idx - L8_OFF;
            v = (e < H) ? b8[e] : w8[e - H];
        } else {                                  // out: b9, pad, w9[10]
            int e = idx - L9_OFF;
            v = (e <= 1) ? b9[0] : w9[e - 2];
        }
        float2 d; d.x = v; d.y = v;
        wp[idx] = d;
    }
}

// ---------------- main kernel: 2 points/thread, VMEM weight delivery ---------
__global__ __launch_bounds__(256, 4) void resnet_fwd(
    const float* __restrict__ x,
    const float2* __restrict__ wp,
    float* __restrict__ out)
{
    // Opaque zero in a VGPR: compiler cannot prove it's 0 or uniform, so all
    // weight-stream accesses become per-lane VMEM loads (same address across
    // the wave -> one L1 line, broadcast to lanes).
    int zot;
    asm("v_mov_b32 %0, 0" : "=v"(zot));
    const float2* wq = wp + zot;

    // 16B load of two duplicated weight pairs from the stream.
    auto ld4 = [&](int idx) -> v4f { return *(const v4f*)(wq + idx); };

    const long i = (long)blockIdx.x * blockDim.x + threadIdx.x;  // pair index
    const float* xp = x + 6 * i;
    v2f X0, X1, X2;
    X0.x = xp[0]; X0.y = xp[3];
    X1.x = xp[1]; X1.y = xp[4];
    X2.x = xp[2]; X2.y = xp[5];

    v2f h[H], t1[H], t2[H];

    // ---- layer 0: 3 -> 10, relu ----
#pragma unroll
    for (int j = 0; j < H; ++j) {
        v4f p = ld4(4 * j);       // bias pair | w_x pair
        v4f q = ld4(4 * j + 2);   // w_y pair  | w_z pair
        v2f a = p.xy;
        a = fma2v(X0, p.zw, a);
        a = fma2v(X1, q.xy, a);
        a = fma2v(X2, q.zw, a);
        h[j] = relu2(a);
    }

    // ---- layer 1: 10 -> 10, relu ----
#pragma unroll
    for (int j = 0; j < H; j += 2) {
        v4f b = ld4(L1_OFF + j);
        t1[j] = b.xy; t1[j + 1] = b.zw;
    }
#pragma unroll
    for (int k = 0; k < H; ++k) {
#pragma unroll
        for (int j = 0; j < H; j += 2) {
            v4f w = ld4(L1_OFF + H + k * H + j);
            t1[j]     = fma2v(h[k], w.xy, t1[j]);
            t1[j + 1] = fma2v(h[k], w.zw, t1[j + 1]);
        }
    }
#pragma unroll
    for (int j = 0; j < H; ++j) h[j] = relu2(t1[j]);

    // ---- L residual blocks ----
#pragma unroll 1
    for (int l = 0; l < L; ++l) {
        const int base = BLK_OFF + l * BLK_STRIDE;

        // t1 = relu(h @ W1 + B1)
#pragma unroll
        for (int j = 0; j < H; j += 2) {
            v4f b = ld4(base + j);
            t1[j] = b.xy; t1[j + 1] = b.zw;
        }
#pragma unroll
        for (int k = 0; k < H; ++k) {
#pragma unroll
            for (int j = 0; j < H; j += 2) {
                v4f w = ld4(base + 10 + k * H + j);
                t1[j]     = fma2v(h[k], w.xy, t1[j]);
                t1[j + 1] = fma2v(h[k], w.zw, t1[j + 1]);
            }
        }
#pragma unroll
        for (int j = 0; j < H; ++j) t1[j] = relu2(t1[j]);

        // t2 = (B2+B3) + h @ W2   (h dies after this)
#pragma unroll
        for (int j = 0; j < H; j += 2) {
            v4f b = ld4(base + 110 + j);
            t2[j] = b.xy; t2[j + 1] = b.zw;
        }
#pragma unroll
        for (int k = 0; k < H; ++k) {
#pragma unroll
            for (int j = 0; j < H; j += 2) {
                v4f w = ld4(base + 120 + k * H + j);
                t2[j]     = fma2v(h[k], w.xy, t2[j]);
                t2[j + 1] = fma2v(h[k], w.zw, t2[j + 1]);
            }
        }

        // t2 += t1 @ W3 ; h = relu(t2)
#pragma unroll
        for (int k = 0; k < H; ++k) {
#pragma unroll
            for (int j = 0; j < H; j += 2) {
                v4f w = ld4(base + 220 + k * H + j);
                t2[j]     = fma2v(t1[k], w.xy, t2[j]);
                t2[j + 1] = fma2v(t1[k], w.zw, t2[j + 1]);
            }
        }
#pragma unroll
        for (int j = 0; j < H; ++j) h[j] = relu2(t2[j]);
    }

    // ---- layer 8: 10 -> 10, relu ----
#pragma unroll
    for (int j = 0; j < H; j += 2) {
        v4f b = ld4(L8_OFF + j);
        t1[j] = b.xy; t1[j + 1] = b.zw;
    }
#pragma unroll
    for (int k = 0; k < H; ++k) {
#pragma unroll
        for (int j = 0; j < H; j += 2) {
            v4f w = ld4(L8_OFF + H + k * H + j);
            t1[j]     = fma2v(h[k], w.xy, t1[j]);
            t1[j + 1] = fma2v(h[k], w.zw, t1[j + 1]);
        }
    }
#pragma unroll
    for (int j = 0; j < H; ++j) h[j] = relu2(t1[j]);

    // ---- output layer: 10 -> 1 ----
    v2f o = tov2(wq[L9_OFF]);
#pragma unroll
    for (int k = 0; k < H; k += 2) {
        v4f w = ld4(L9_OFF + 2 + k);
        o = fma2v(h[k],     w.xy, o);
        o = fma2v(h[k + 1], w.zw, o);
    }

    *(v2f*)(out + 2 * i) = o;
}

extern "C" void kernel_launch(void* const* d_in, const int* in_sizes, int n_in,
                              void* d_out, int out_size, void* d_ws, size_t ws_size,
                              hipStream_t stream)
{
    const float* x   = (const float*)d_in[0];
    const float* w0  = (const float*)d_in[1];
    const float* b0  = (const float*)d_in[2];
    const float* w1  = (const float*)d_in[3];
    const float* b1  = (const float*)d_in[4];
    const float* Wr1 = (const float*)d_in[5];
    const float* Br1 = (const float*)d_in[6];
    const float* Wr2 = (const float*)d_in[7];
    const float* Br2 = (const float*)d_in[8];
    const float* Wr3 = (const float*)d_in[9];
    const float* Br3 = (const float*)d_in[10];
    const float* w8  = (const float*)d_in[11];
    const float* b8  = (const float*)d_in[12];
    const float* w9  = (const float*)d_in[13];
    const float* b9  = (const float*)d_in[14];
    float* out = (float*)d_out;
    float2* wp = (float2*)d_ws;   // 3472 * 8 B = 27.8 KB scratch

    hipLaunchKernelGGL(prepack, dim3(1), dim3(256), 0, stream,
                       w0, b0, w1, b1, Wr1, Br1, Wr2, Br2, Wr3, Br3,
                       w8, b8, w9, b9, wp);

    dim3 block(256);
    dim3 grid(NPTS / 2 / 256);   // 2 points per thread
    hipLaunchKernelGGL(resnet_fwd, grid, block, 0, stream,
                       x, (const float2*)wp, out);
}

// Round 9
// 391.787 us; speedup vs baseline: 4.1552x; 4.1552x over previous
//
#include <hip/hip_runtime.h>

// ResidualNetwork forward, fp32, MI355X (gfx950).
// Round 9: HYBRID weight delivery — balance the per-SIMD VALU pipe against the
// per-CU DS pipe. Delivery ledger (measured): scalar path ~2cyc/pair extra on
// VALU (r3; compiler mixes direct-SGPR-pair pk_fma + movs); LDS broadcast
// ~2.55cyc/pair on the shared DS pipe (r4: all-DS = 1.135M cyc/CU = 473us);
// VMEM per-lane uniform loads = latency-serialized disaster (r8, 1607us).
// Split: f=0.654 of the stream via LDS (layer0, all biases, W1, W2), rest via
// global s_load (w1, W3, w8). P=4 points/thread amortizes the V-path mov tax.
// DS/CU ~ 392k cyc < VALU/SIMD ~ 510k cyc = 213us busy -> 225-245us wall.
// amdgpu_waves_per_eu(2,4): stop the scheduler from crushing VGPRs to 64 for
// 8-wave occupancy (r6's serialization) — occupancy >4/EU is worthless here.
// Stream (float2 dup pairs (w,w)), d_ws:
//   S (staged to LDS) [0,2272): l0[40] | b1[10] | 10x{B1[10] W1[100] B23[10]
//                               W2[100]} | b8[10] | {b9,pad,w9[10]}
//   V (global)     [2272,3472): w1[100] | 10x{W3[100]} | w8[100]

#define NPTS 4194304
#define H 10
#define L 10

#define S_B1   40
#define S_BLK  50
#define S_BSTR 220
#define S_B8   2250
#define S_OUT  2260
#define NS     2272
#define V_W3   100
#define V_W8   1100
#define NENT   3472

typedef float v2f __attribute__((ext_vector_type(2)));
typedef float v4f __attribute__((ext_vector_type(4)));

__device__ __forceinline__ v2f tov2(float2 w) { v2f r; r.x = w.x; r.y = w.y; return r; }
__device__ __forceinline__ v2f bc(float s) { v2f r; r.x = s; r.y = s; return r; }
__device__ __forceinline__ v2f fma2v(v2f a, v2f w, v2f c) {
    return __builtin_elementwise_fma(a, w, c);
}
__device__ __forceinline__ v2f relu2(v2f a) {
    return __builtin_elementwise_max(a, bc(0.0f));
}

// ---------------- prepack: weights -> two use-order duplicated-pair streams --
__global__ __launch_bounds__(256) void prepack(
    const float* __restrict__ w0, const float* __restrict__ b0,
    const float* __restrict__ w1, const float* __restrict__ b1,
    const float* __restrict__ Wr1, const float* __restrict__ Br1,
    const float* __restrict__ Wr2, const float* __restrict__ Br2,
    const float* __restrict__ Wr3, const float* __restrict__ Br3,
    const float* __restrict__ w8, const float* __restrict__ b8,
    const float* __restrict__ w9, const float* __restrict__ b9,
    float2* __restrict__ wp)
{
    for (int idx = threadIdx.x; idx < NENT; idx += 256) {
        float v;
        if (idx < 40) {                           // layer0: b, w0x, w0y, w0z per j
            int j = idx >> 2, r = idx & 3;
            v = (r == 0) ? b0[j] : w0[(r - 1) * H + j];
        } else if (idx < S_BLK) {                 // b1
            v = b1[idx - S_B1];
        } else if (idx < S_B8) {                  // blocks: B1 | W1 | B23 | W2
            int e = idx - S_BLK;
            int l = e / S_BSTR, m = e % S_BSTR;
            if      (m < 10)  v = Br1[l * H + m];
            else if (m < 110) v = Wr1[l * H * H + (m - 10)];
            else if (m < 120) v = Br2[l * H + (m - 110)] + Br3[l * H + (m - 110)];
            else              v = Wr2[l * H * H + (m - 120)];
        } else if (idx < S_OUT) {                 // b8
            v = b8[idx - S_B8];
        } else if (idx < NS) {                    // out: b9, pad, w9[10]
            int e = idx - S_OUT;
            v = (e <= 1) ? b9[0] : w9[e - 2];
        } else {                                  // V-stream: w1 | W3 x10 | w8
            int e = idx - NS;
            if      (e < V_W3) v = w1[e];
            else if (e < V_W8) v = Wr3[((e - V_W3) / 100) * H * H + (e - V_W3) % 100];
            else               v = w8[e - V_W8];
        }
        float2 d; d.x = v; d.y = v;
        wp[idx] = d;
    }
}

// ---------------- main kernel: 4 points/thread, hybrid LDS+scalar weights ----
__global__ __launch_bounds__(256)
__attribute__((amdgpu_waves_per_eu(2, 4)))
void resnet_fwd(
    const float* __restrict__ x,
    const float2* __restrict__ wp,
    float* __restrict__ out)
{
    __shared__ __align__(16) float2 slds[NS];

    // stage S-stream into LDS (18.2 KB / WG)
    for (int idx = threadIdx.x; idx < NS; idx += 256)
        slds[idx] = wp[idx];
    __syncthreads();

    const float2* __restrict__ wv = wp + NS;   // V-stream stays in global (s_load path)

    auto lds4 = [&](int p) -> v4f { return *(const v4f*)(slds + p); };   // p even
    auto ldsp = [&](int p) -> v2f { return tov2(slds[p]); };

    const long i = (long)blockIdx.x * blockDim.x + threadIdx.x;  // quad index
    const float* xp = x + 12 * i;
    v2f XA0, XA1, XA2, XB0, XB1, XB2;
    XA0.x = xp[0]; XA0.y = xp[3];  XB0.x = xp[6]; XB0.y = xp[9];
    XA1.x = xp[1]; XA1.y = xp[4];  XB1.x = xp[7]; XB1.y = xp[10];
    XA2.x = xp[2]; XA2.y = xp[5];  XB2.x = xp[8]; XB2.y = xp[11];

    v2f hA[H], hB[H], t1A[H], t1B[H], t2A[H], t2B[H];

    // ---- layer 0: 3 -> 10, relu (all LDS) ----
#pragma unroll
    for (int j = 0; j < H; ++j) {
        v4f p = lds4(4 * j);       // bias | w_x
        v4f q = lds4(4 * j + 2);   // w_y  | w_z
        v2f a = p.xy, c = p.xy;
        a = fma2v(XA0, p.zw, a);  c = fma2v(XB0, p.zw, c);
        a = fma2v(XA1, q.xy, a);  c = fma2v(XB1, q.xy, c);
        a = fma2v(XA2, q.zw, a);  c = fma2v(XB2, q.zw, c);
        hA[j] = relu2(a);
        hB[j] = relu2(c);
    }

    // ---- layer 1: 10 -> 10, relu (bias LDS, weights V) ----
#pragma unroll
    for (int j = 0; j < H; ++j) {
        v2f b = ldsp(S_B1 + j);
        t1A[j] = b; t1B[j] = b;
    }
#pragma unroll
    for (int k = 0; k < H; ++k) {
#pragma unroll
        for (int j = 0; j < H; ++j) {
            v2f w = tov2(wv[k * H + j]);
            t1A[j] = fma2v(hA[k], w, t1A[j]);
            t1B[j] = fma2v(hB[k], w, t1B[j]);
        }
    }
#pragma unroll
    for (int j = 0; j < H; ++j) { hA[j] = relu2(t1A[j]); hB[j] = relu2(t1B[j]); }

    // ---- L residual blocks ----
#pragma unroll 1
    for (int l = 0; l < L; ++l) {
        const int sb = S_BLK + l * S_BSTR;           // LDS: B1 W1 B23 W2
        const float2* __restrict__ w3 = wv + V_W3 + l * 100;  // global: W3

        // t1 = relu(h @ W1 + B1)   [W1 via LDS]
#pragma unroll
        for (int j = 0; j < H; ++j) {
            v2f b = ldsp(sb + j);
            t1A[j] = b; t1B[j] = b;
        }
#pragma unroll
        for (int k = 0; k < H; ++k) {
#pragma unroll
            for (int j = 0; j < H; j += 2) {
                v4f w = lds4(sb + 10 + k * H + j);
                t1A[j]     = fma2v(hA[k], w.xy, t1A[j]);
                t1B[j]     = fma2v(hB[k], w.xy, t1B[j]);
                t1A[j + 1] = fma2v(hA[k], w.zw, t1A[j + 1]);
                t1B[j + 1] = fma2v(hB[k], w.zw, t1B[j + 1]);
            }
        }
#pragma unroll
        for (int j = 0; j < H; ++j) { t1A[j] = relu2(t1A[j]); t1B[j] = relu2(t1B[j]); }

        // t2 = (B2+B3) + h @ W2   [W2 via LDS; h dies after this]
#pragma unroll
        for (int j = 0; j < H; ++j) {
            v2f b = ldsp(sb + 110 + j);
            t2A[j] = b; t2B[j] = b;
        }
#pragma unroll
        for (int k = 0; k < H; ++k) {
#pragma unroll
            for (int j = 0; j < H; j += 2) {
                v4f w = lds4(sb + 120 + k * H + j);
                t2A[j]     = fma2v(hA[k], w.xy, t2A[j]);
                t2B[j]     = fma2v(hB[k], w.xy, t2B[j]);
                t2A[j + 1] = fma2v(hA[k], w.zw, t2A[j + 1]);
                t2B[j + 1] = fma2v(hB[k], w.zw, t2B[j + 1]);
            }
        }

        // t2 += t1 @ W3 ; h = relu(t2)   [W3 via global scalar path]
#pragma unroll
        for (int k = 0; k < H; ++k) {
#pragma unroll
            for (int j = 0; j < H; ++j) {
                v2f w = tov2(w3[k * H + j]);
                t2A[j] = fma2v(t1A[k], w, t2A[j]);
                t2B[j] = fma2v(t1B[k], w, t2B[j]);
            }
        }
#pragma unroll
        for (int j = 0; j < H; ++j) { hA[j] = relu2(t2A[j]); hB[j] = relu2(t2B[j]); }
    }

    // ---- layer 8: 10 -> 10, relu (bias LDS, weights V) ----
#pragma unroll
    for (int j = 0; j < H; ++j) {
        v2f b = ldsp(S_B8 + j);
        t1A[j] = b; t1B[j] = b;
    }
#pragma unroll
    for (int k = 0; k < H; ++k) {
#pragma unroll
        for (int j = 0; j < H; ++j) {
            v2f w = tov2(wv[V_W8 + k * H + j]);
            t1A[j] = fma2v(hA[k], w, t1A[j]);
            t1B[j] = fma2v(hB[k], w, t1B[j]);
        }
    }
#pragma unroll
    for (int j = 0; j < H; ++j) { hA[j] = relu2(t1A[j]); hB[j] = relu2(t1B[j]); }

    // ---- output layer: 10 -> 1 (LDS) ----
    v2f ob = ldsp(S_OUT);
    v2f oA = ob, oB = ob;
#pragma unroll
    for (int k = 0; k < H; ++k) {
        v2f w = ldsp(S_OUT + 2 + k);
        oA = fma2v(hA[k], w, oA);
        oB = fma2v(hB[k], w, oB);
    }

    v4f o; o.x = oA.x; o.y = oA.y; o.z = oB.x; o.w = oB.y;
    *(v4f*)(out + 4 * i) = o;
}

extern "C" void kernel_launch(void* const* d_in, const int* in_sizes, int n_in,
                              void* d_out, int out_size, void* d_ws, size_t ws_size,
                              hipStream_t stream)
{
    const float* x   = (const float*)d_in[0];
    const float* w0  = (const float*)d_in[1];
    const float* b0  = (const float*)d_in[2];
    const float* w1  = (const float*)d_in[3];
    const float* b1  = (const float*)d_in[4];
    const float* Wr1 = (const float*)d_in[5];
    const float* Br1 = (const float*)d_in[6];
    const float* Wr2 = (const float*)d_in[7];
    const float* Br2 = (const float*)d_in[8];
    const float* Wr3 = (const float*)d_in[9];
    const float* Br3 = (const float*)d_in[10];
    const float* w8  = (const float*)d_in[11];
    const float* b8  = (const float*)d_in[12];
    const float* w9  = (const float*)d_in[13];
    const float* b9  = (const float*)d_in[14];
    float* out = (float*)d_out;
    float2* wp = (float2*)d_ws;   // 3472 * 8 B = 27.8 KB scratch

    hipLaunchKernelGGL(prepack, dim3(1), dim3(256), 0, stream,
                       w0, b0, w1, b1, Wr1, Br1, Wr2, Br2, Wr3, Br3,
                       w8, b8, w9, b9, wp);

    dim3 block(256);
    dim3 grid(NPTS / 4 / 256);   // 4 points per thread
    hipLaunchKernelGGL(resnet_fwd, grid, block, 0, stream,
                       x, (const float2*)wp, out);
}

// Round 10
// 363.089 us; speedup vs baseline: 4.4836x; 1.0790x over previous
//
#include <hip/hip_runtime.h>

// ResidualNetwork forward, MI355X (gfx950).
// Round 10: switch the MAC engine from v_pk_fma_f32 (half-rate, fp32 floor
// 414.7k cyc/SIMD = 173us) to v_dot2_f32_f16 (__builtin_amdgcn_fdot2):
// 2 MACs/instr, f16 inputs, EXACT fp32 accumulate -> MAC floor halves to 86us.
// Only error: h/w/x rounded to f16 (RN) once per use; est absmax 1e-3..5e-3.
// K-packing: h as 5 half2; biases folded into the stream as (b,0) pairs
// consumed by constant ONE=(1,0) -> zero bias movs. P=4 points/thread
// amortizes weight materialization (1 mov per half2 weight feeds 4 dot2).
// Ledger: LDS delivery = per-CU DS pipe saturates/latency (r4/r9); SGPR
// pinning = spills (r5); VMEM uniform = latency disaster (r8); scalar-path
// mov tax ~2cyc/weight-VGPR is acceptable only when amortized (r6).
// Model/SIMD: dot2 236k + cvt/relu 42k + wmov 59k + misc ~15k = 352k cyc
// = 147us busy -> 150-180us wall.

#define NPTS 4194304
#define P 4
#define L 10

#define L0S 0
#define L1S 20
#define BLKS 80
#define BSTR 170
#define L8S 1780
#define L9S 1840
#define NE 1846

typedef _Float16 h2 __attribute__((ext_vector_type(2)));
typedef float v4f __attribute__((ext_vector_type(4)));

#if defined(__has_builtin)
#if __has_builtin(__builtin_amdgcn_fdot2)
#define HAVE_FDOT2 1
#endif
#endif

__device__ __forceinline__ float dot2(h2 a, h2 b, float c) {
#ifdef HAVE_FDOT2
    return __builtin_amdgcn_fdot2(a, b, c, false);
#else
    return fmaf((float)a.x, (float)b.x, fmaf((float)a.y, (float)b.y, c));
#endif
}

// ---------------- prepack: weights -> f16 k-pair stream, use order -----------
// half2 entries:
//  [0,20)    layer0, per j: (w0[0][j],w0[1][j]), (w0[2][j], b0[j])
//  [20,80)   layer1, per j: (b1[j],0), 5x(w1[2k][j],w1[2k+1][j])
//  [80,1780) 10 blocks x 170: W1-sec 60 (bias B1 folded), W2-sec 60 (bias
//            B2+B3 folded), W3-sec 50 (per j: 5 pairs, no bias)
//  [1780,1840) layer8 like layer1
//  [1840,1846) out: (b9,0), 5x(w9[2k],w9[2k+1])
__global__ __launch_bounds__(256) void prepack(
    const float* __restrict__ w0, const float* __restrict__ b0,
    const float* __restrict__ w1, const float* __restrict__ b1,
    const float* __restrict__ Wr1, const float* __restrict__ Br1,
    const float* __restrict__ Wr2, const float* __restrict__ Br2,
    const float* __restrict__ Wr3, const float* __restrict__ Br3,
    const float* __restrict__ w8, const float* __restrict__ b8,
    const float* __restrict__ w9, const float* __restrict__ b9,
    h2* __restrict__ wp)
{
    for (int idx = threadIdx.x; idx < NE; idx += 256) {
        float a, b;
        if (idx < L1S) {                          // layer0
            int j = idx >> 1;
            if (idx & 1) { a = w0[20 + j]; b = b0[j]; }
            else         { a = w0[j];      b = w0[10 + j]; }
        } else if (idx < BLKS) {                  // layer1
            int e = idx - L1S, j = e / 6, m = e % 6;
            if (m == 0) { a = b1[j]; b = 0.0f; }
            else { int kp = m - 1; a = w1[(2*kp)*10 + j]; b = w1[(2*kp+1)*10 + j]; }
        } else if (idx < L8S) {                   // residual blocks
            int e = idx - BLKS, l = e / BSTR, m = e % BSTR;
            if (m < 60) {
                int j = m / 6, mm = m % 6;
                if (mm == 0) { a = Br1[l*10 + j]; b = 0.0f; }
                else { int kp = mm - 1;
                       a = Wr1[l*100 + (2*kp)*10 + j];
                       b = Wr1[l*100 + (2*kp+1)*10 + j]; }
            } else if (m < 120) {
                int m2 = m - 60, j = m2 / 6, mm = m2 % 6;
                if (mm == 0) { a = Br2[l*10 + j] + Br3[l*10 + j]; b = 0.0f; }
                else { int kp = mm - 1;
                       a = Wr2[l*100 + (2*kp)*10 + j];
                       b = Wr2[l*100 + (2*kp+1)*10 + j]; }
            } else {
                int m3 = m - 120, j = m3 / 5, kp = m3 % 5;
                a = Wr3[l*100 + (2*kp)*10 + j];
                b = Wr3[l*100 + (2*kp+1)*10 + j];
            }
        } else if (idx < L9S) {                   // layer8
            int e = idx - L8S, j = e / 6, m = e % 6;
            if (m == 0) { a = b8[j]; b = 0.0f; }
            else { int kp = m - 1; a = w8[(2*kp)*10 + j]; b = w8[(2*kp+1)*10 + j]; }
        } else {                                  // output layer
            int e = idx - L9S;
            if (e == 0) { a = b9[0]; b = 0.0f; }
            else { int kp = e - 1; a = w9[2*kp]; b = w9[2*kp+1]; }
        }
        h2 v; v.x = (_Float16)a; v.y = (_Float16)b;
        wp[idx] = v;
    }
}

// ---------------- main kernel: 4 points/thread, f16 dot2 ---------------------
__global__ __launch_bounds__(256, 2) void resnet_fwd(
    const float* __restrict__ x,
    const h2* __restrict__ wp,
    float* __restrict__ out)
{
    const long i = (long)blockIdx.x * blockDim.x + threadIdx.x;  // quad index
    const float* xp = x + 12 * i;

    h2 ONE; ONE.x = (_Float16)1.0f; ONE.y = (_Float16)0.0f;

    h2 hp[P][5];

    // dense 10->10 with folded bias: acc[p][j] = B[j] + sum_k hin[p][k]*W[k][j]
    auto dense10 = [&](int base, h2 (&hin)[P][5], float (&acc)[P][10]) {
#pragma unroll
        for (int j = 0; j < 10; ++j) {
#pragma unroll
            for (int p = 0; p < P; ++p) {
                float a = dot2(ONE, wp[base + 6*j], 0.0f);
#pragma unroll
                for (int kp = 0; kp < 5; ++kp)
                    a = dot2(hin[p][kp], wp[base + 6*j + 1 + kp], a);
                acc[p][j] = a;
            }
        }
    };
    // relu in fp32, pack to f16 k-pairs (RN converts)
    auto packrelu = [&](float (&acc)[P][10], h2 (&hout)[P][5]) {
#pragma unroll
        for (int p = 0; p < P; ++p)
#pragma unroll
            for (int m = 0; m < 5; ++m) {
                h2 r;
                r.x = (_Float16)fmaxf(acc[p][2*m],     0.0f);
                r.y = (_Float16)fmaxf(acc[p][2*m + 1], 0.0f);
                hout[p][m] = r;
            }
    };

    // ---- layer 0: 3 -> 10 (bias folded into (w2,b) pair vs (x2,1)) ----
    {
        float acc[P][10];
#pragma unroll
        for (int p = 0; p < P; ++p) {
            h2 x01, x2b;
            x01.x = (_Float16)xp[3*p + 0];
            x01.y = (_Float16)xp[3*p + 1];
            x2b.x = (_Float16)xp[3*p + 2];
            x2b.y = (_Float16)1.0f;
#pragma unroll
            for (int j = 0; j < 10; ++j) {
                float a = dot2(x01, wp[L0S + 2*j], 0.0f);
                a = dot2(x2b, wp[L0S + 2*j + 1], a);
                acc[p][j] = a;
            }
        }
        packrelu(acc, hp);
    }

    // ---- layer 1 ----
    {
        float acc[P][10];
        dense10(L1S, hp, acc);
        packrelu(acc, hp);
    }

    // ---- L residual blocks ----
#pragma unroll 1
    for (int l = 0; l < L; ++l) {
        const int b1 = BLKS + l * BSTR;

        float t1[P][10];
        dense10(b1, hp, t1);          // h @ W1 + B1
        h2 t1p[P][5];
        packrelu(t1, t1p);

        float t2[P][10];
        dense10(b1 + 60, hp, t2);     // h @ W2 + (B2+B3)
#pragma unroll
        for (int j = 0; j < 10; ++j) {
#pragma unroll
            for (int p = 0; p < P; ++p) {
                float a = t2[p][j];
#pragma unroll
                for (int kp = 0; kp < 5; ++kp)
                    a = dot2(t1p[p][kp], wp[b1 + 120 + 5*j + kp], a);
                t2[p][j] = a;
            }
        }
        packrelu(t2, hp);
    }

    // ---- layer 8 ----
    {
        float acc[P][10];
        dense10(L8S, hp, acc);
        packrelu(acc, hp);
    }

    // ---- output layer: 10 -> 1 ----
    v4f o;
#pragma unroll
    for (int p = 0; p < P; ++p) {
        float a = dot2(ONE, wp[L9S], 0.0f);
#pragma unroll
        for (int kp = 0; kp < 5; ++kp)
            a = dot2(hp[p][kp], wp[L9S + 1 + kp], a);
        o[p] = a;
    }
    *(v4f*)(out + 4 * i) = o;
}

extern "C" void kernel_launch(void* const* d_in, const int* in_sizes, int n_in,
                              void* d_out, int out_size, void* d_ws, size_t ws_size,
                              hipStream_t stream)
{
    const float* x   = (const float*)d_in[0];
    const float* w0  = (const float*)d_in[1];
    const float* b0  = (const float*)d_in[2];
    const float* w1  = (const float*)d_in[3];
    const float* b1  = (const float*)d_in[4];
    const float* Wr1 = (const float*)d_in[5];
    const float* Br1 = (const float*)d_in[6];
    const float* Wr2 = (const float*)d_in[7];
    const float* Br2 = (const float*)d_in[8];
    const float* Wr3 = (const float*)d_in[9];
    const float* Br3 = (const float*)d_in[10];
    const float* w8  = (const float*)d_in[11];
    const float* b8  = (const float*)d_in[12];
    const float* w9  = (const float*)d_in[13];
    const float* b9  = (const float*)d_in[14];
    float* out = (float*)d_out;
    h2* wp = (h2*)d_ws;   // 1846 * 4 B = 7.4 KB scratch

    hipLaunchKernelGGL(prepack, dim3(1), dim3(256), 0, stream,
                       w0, b0, w1, b1, Wr1, Br1, Wr2, Br2, Wr3, Br3,
                       w8, b8, w9, b9, wp);

    dim3 block(256);
    dim3 grid(NPTS / P / 256);   // 4 points per thread
    hipLaunchKernelGGL(resnet_fwd, grid, block, 0, stream,
                       x, (const h2*)wp, out);
}

// Round 11
// 256.413 us; speedup vs baseline: 6.3490x; 1.4160x over previous
//
#include <hip/hip_runtime.h>

// ResidualNetwork forward, MI355X (gfx950).
// Round 11: MOVE TO THE MATRIX PIPE. Session ledger proved every VALU dtype
// is issue-capped at ~157 TF (pk_fma_f32 and dot2_f16 both 4cyc/2MAC): hard
// 173us MAC floor, r6=276us is floor+mov tax. MfmaUtil has been 0 all along.
// Scheme: v_mfma_f32_16x16x16_f16 per layer, D = A(W^T)*B(h^T).
//   KEY: C/D layout (row=(lane>>4)*4+reg, col=lane&15) == B-operand layout
//   (k=(lane>>4)*4+j, n=lane&15) for this shape -> relu+cvt of D IN-LANE is
//   the next layer's B fragment. No LDS, no cross-lane, no per-layer weight
//   traffic (A fragments preloaded once per wave: 34 x 8B/lane, per-lane
//   distinct addresses = real vector loads, not r8's uniform-load trap).
// Bias: ones-row trick. B row 10 = 1 (row 3 for layer0's x). A col 10 = bias,
// A[10][10] = 1 propagates the ones-row (relu(1)=1). W3 fragment has no bias
// col / no pass row; residual = two MFMAs chained through the C accumulator.
// 34 MFMA / 16-point tile; 2 independent tiles interleaved per wave (ILP).
// Budget/SIMD: MFMA 37k cyc (15us) | VALU relu/cvt ~97k (40us) | mem 10us.

#define NPTS 4194304
#define NTILES (NPTS / 16)          // 262144
#define NWAVES 4096                 // 1024 blocks x 4 waves
#define TPW (NTILES / NWAVES)       // 64 tiles per wave
#define NMM 34                      // matmul fragments

typedef _Float16 h4 __attribute__((ext_vector_type(4)));
typedef float v4f __attribute__((ext_vector_type(4)));

__device__ __forceinline__ v4f mm(h4 a, h4 b, v4f c) {
    return __builtin_amdgcn_mfma_f32_16x16x16f16(a, b, c, 0, 0, 0);
}
__device__ __forceinline__ h4 relu_cvt(v4f d) {
    h4 r;
#pragma unroll
    for (int j = 0; j < 4; ++j) r[j] = (_Float16)fmaxf(d[j], 0.0f);
    return r;
}

// ---------------- prepack: per-lane A-operand fragments ----------------------
// A_q is 16x16 f16, A[m][k]; lane l supplies A[m=l&15][k=(l>>4)*4+j], j=0..3.
// tab[q*64 + l] = those 4 f16 (8B).
// q=0: layer0  A[m][k]=w0[k][m] (k<3), A[m][3]=b0[m], A[10][3]=1
// q=1: layer1  dense(w1,b1):  A[m][k]=W[k][m] (k,m<10), A[m][10]=b, A[10][10]=1
// q=2+3l,3+3l: dense(Wr1,Br1), dense(Wr2,Br2+Br3)
// q=4+3l:      W3-type: A[m][k]=Wr3[k][m] only (no bias, no pass)
// q=32: dense(w8,b8)   q=33: out row: A[0][k]=w9[k] (k<10), A[0][10]=b9
__global__ __launch_bounds__(256) void prepack(
    const float* __restrict__ w0, const float* __restrict__ b0,
    const float* __restrict__ w1, const float* __restrict__ b1,
    const float* __restrict__ Wr1, const float* __restrict__ Br1,
    const float* __restrict__ Wr2, const float* __restrict__ Br2,
    const float* __restrict__ Wr3, const float* __restrict__ Br3,
    const float* __restrict__ w8, const float* __restrict__ b8,
    const float* __restrict__ w9, const float* __restrict__ b9,
    h4* __restrict__ tab)
{
    for (int e = threadIdx.x; e < NMM * 64; e += 256) {
        const int q = e >> 6, l = e & 63;
        const int m = l & 15, kq = l >> 4;
        h4 v;
#pragma unroll
        for (int j = 0; j < 4; ++j) {
            const int k = kq * 4 + j;
            float a = 0.0f;
            if (q == 0) {
                if (m < 10 && k < 3)       a = w0[k * 10 + m];
                else if (m < 10 && k == 3) a = b0[m];
                else if (m == 10 && k == 3) a = 1.0f;
            } else if (q == 33) {
                if (m == 0 && k < 10)       a = w9[k];
                else if (m == 0 && k == 10) a = b9[0];
            } else {
                const float* W = nullptr;
                float bias = 0.0f;
                bool hasB = true, pass = true;
                if (q == 1)       { W = w1; bias = (m < 10) ? b1[m] : 0.0f; }
                else if (q == 32) { W = w8; bias = (m < 10) ? b8[m] : 0.0f; }
                else {
                    const int qq = q - 2, bl = qq / 3, r = qq % 3;
                    if (r == 0)      { W = Wr1 + bl * 100; bias = (m < 10) ? Br1[bl * 10 + m] : 0.0f; }
                    else if (r == 1) { W = Wr2 + bl * 100; bias = (m < 10) ? Br2[bl * 10 + m] + Br3[bl * 10 + m] : 0.0f; }
                    else             { W = Wr3 + bl * 100; hasB = false; pass = false; }
                }
                if (m < 10 && k < 10)            a = W[k * 10 + m];
                else if (m < 10 && k == 10 && hasB)  a = bias;
                else if (m == 10 && k == 10 && pass) a = 1.0f;
            }
            v[j] = (_Float16)a;
        }
        tab[e] = v;
    }
}

// ---------------- main kernel: MFMA layer chain, 2 tiles interleaved ---------
__global__ __launch_bounds__(256, 3) void resnet_fwd(
    const float* __restrict__ x,
    const h4* __restrict__ tab,
    float* __restrict__ out)
{
    const int lane = threadIdx.x & 63;
    const int wg = blockIdx.x * 4 + (threadIdx.x >> 6);
    const bool lo = lane < 16;

    // preload all weight fragments (per-lane addresses, one-time)
    h4 wA[NMM];
#pragma unroll
    for (int q = 0; q < NMM; ++q) wA[q] = tab[q * 64 + lane];

    const v4f zero = {0.0f, 0.0f, 0.0f, 0.0f};
    const long tile0 = (long)wg * TPW;

    for (int t = 0; t < TPW; t += 2) {
        const long baseA = (tile0 + t) * 16;
        const long baseB = (tile0 + t + 1) * 16;

        // build layer-0 B fragments: quad0 lanes carry (x0,x1,x2,1), rest 0
        float a0 = 0, a1 = 0, a2 = 0, c0 = 0, c1 = 0, c2 = 0;
        if (lo) {
            const float* pA = x + (baseA + lane) * 3;
            a0 = pA[0]; a1 = pA[1]; a2 = pA[2];
            const float* pB = x + (baseB + lane) * 3;
            c0 = pB[0]; c1 = pB[1]; c2 = pB[2];
        }
        h4 bxA, bxB;
        bxA[0] = (_Float16)a0; bxA[1] = (_Float16)a1; bxA[2] = (_Float16)a2;
        bxA[3] = lo ? (_Float16)1.0f : (_Float16)0.0f;
        bxB[0] = (_Float16)c0; bxB[1] = (_Float16)c1; bxB[2] = (_Float16)c2;
        bxB[3] = lo ? (_Float16)1.0f : (_Float16)0.0f;

        // layer 0, layer 1
        v4f dA = mm(wA[0], bxA, zero);
        v4f dB = mm(wA[0], bxB, zero);
        h4 hA = relu_cvt(dA);
        h4 hB = relu_cvt(dB);
        dA = mm(wA[1], hA, zero);
        dB = mm(wA[1], hB, zero);
        hA = relu_cvt(dA);
        hB = relu_cvt(dB);

        // residual blocks (fully unrolled so wA indices are constants)
#pragma unroll
        for (int bl = 0; bl < 10; ++bl) {
            v4f d1A = mm(wA[2 + 3 * bl], hA, zero);
            v4f d1B = mm(wA[2 + 3 * bl], hB, zero);
            v4f d2A = mm(wA[3 + 3 * bl], hA, zero);
            v4f d2B = mm(wA[3 + 3 * bl], hB, zero);
            h4 t1A = relu_cvt(d1A);
            h4 t1B = relu_cvt(d1B);
            d2A = mm(wA[4 + 3 * bl], t1A, d2A);
            d2B = mm(wA[4 + 3 * bl], t1B, d2B);
            hA = relu_cvt(d2A);
            hB = relu_cvt(d2B);
        }

        // layer 8
        dA = mm(wA[32], hA, zero);
        dB = mm(wA[32], hB, zero);
        hA = relu_cvt(dA);
        hB = relu_cvt(dB);

        // output layer: row 0 of D = result for the 16 points
        dA = mm(wA[33], hA, zero);
        dB = mm(wA[33], hB, zero);
        if (lo) {
            out[baseA + lane] = dA[0];
            out[baseB + lane] = dB[0];
        }
    }
}

extern "C" void kernel_launch(void* const* d_in, const int* in_sizes, int n_in,
                              void* d_out, int out_size, void* d_ws, size_t ws_size,
                              hipStream_t stream)
{
    const float* x   = (const float*)d_in[0];
    const float* w0  = (const float*)d_in[1];
    const float* b0  = (const float*)d_in[2];
    const float* w1  = (const float*)d_in[3];
    const float* b1  = (const float*)d_in[4];
    const float* Wr1 = (const float*)d_in[5];
    const float* Br1 = (const float*)d_in[6];
    const float* Wr2 = (const float*)d_in[7];
    const float* Br2 = (const float*)d_in[8];
    const float* Wr3 = (const float*)d_in[9];
    const float* Br3 = (const float*)d_in[10];
    const float* w8  = (const float*)d_in[11];
    const float* b8  = (const float*)d_in[12];
    const float* w9  = (const float*)d_in[13];
    const float* b9  = (const float*)d_in[14];
    float* out = (float*)d_out;
    h4* tab = (h4*)d_ws;   // 34 * 64 * 8B = 17.4 KB scratch

    hipLaunchKernelGGL(prepack, dim3(1), dim3(256), 0, stream,
                       w0, b0, w1, b1, Wr1, Br1, Wr2, Br2, Wr3, Br3,
                       w8, b8, w9, b9, tab);

    hipLaunchKernelGGL(resnet_fwd, dim3(NWAVES / 4), dim3(256), 0, stream,
                       x, (const h4*)tab, out);
}

// Round 12
// 247.840 us; speedup vs baseline: 6.5686x; 1.0346x over previous
//
#include <hip/hip_runtime.h>

// ResidualNetwork forward, MI355X (gfx950).
// Round 12: r11 MFMA chain (D->B in-lane identity for 16x16x16_f16, ones-row
// bias trick, weights A-stationary in regs) with the two measured overheads
// attacked:
//  (a) relu_cvt was ~24 VALU instr (scalarized cvt+insert, 291k cyc/SIMD =
//      73% busy). Now: 2x v_pk_max_f32 + 2x v_cvt_pkrtz_f16_f32 + pack = ~5.
//      RTZ vs RN: f16 RN passed with absmax 0.0; 1-ulp-f16 class difference.
//  (b) latency exposure at ~32% occupancy: 4 independent tile-chains per wave
//      (ILP 4) + 2048 blocks (TPW=32) for load balance.
// Probe intent: separates "legacy K=16 MFMA is quarter-rate (~16cyc)" from
// "pipe idled on deps". If MfmaUtil>=45% & wall 75-95us -> K=16 slow, next
// round = 32x32x16 shape. If wall 45-60us & MfmaUtil<=30% -> near floor.

#define NPTS 4194304
#define NBLK 2048
#define NWAVES (NBLK * 4)           // 8192
#define NTILES (NPTS / 16)          // 262144
#define TPW (NTILES / NWAVES)       // 32 tiles per wave
#define NMM 34                      // matmul fragments
#define ILP 4

typedef _Float16 h4 __attribute__((ext_vector_type(4)));
typedef float v4f __attribute__((ext_vector_type(4)));
typedef unsigned u2v __attribute__((ext_vector_type(2)));

__device__ __forceinline__ v4f mm(h4 a, h4 b, v4f c) {
    return __builtin_amdgcn_mfma_f32_16x16x16f16(a, b, c, 0, 0, 0);
}
// relu in fp32 (pk_max) then pack-convert to f16 (cvt_pkrtz).
// max(cvt(x),0)==cvt(max(x,0)) (monotone, cvt(0)=0), so relu-then-cvt is
// exactly the reference relu up to the f16 rounding we already carry.
__device__ __forceinline__ h4 relu_cvt(v4f d) {
    const v4f z = {0.0f, 0.0f, 0.0f, 0.0f};
    v4f m = __builtin_elementwise_max(d, z);
    u2v u;
    u.x = __builtin_bit_cast(unsigned, __builtin_amdgcn_cvt_pkrtz(m.x, m.y));
    u.y = __builtin_bit_cast(unsigned, __builtin_amdgcn_cvt_pkrtz(m.z, m.w));
    return __builtin_bit_cast(h4, u);
}

// ---------------- prepack: per-lane A-operand fragments (same as r11) --------
__global__ __launch_bounds__(256) void prepack(
    const float* __restrict__ w0, const float* __restrict__ b0,
    const float* __restrict__ w1, const float* __restrict__ b1,
    const float* __restrict__ Wr1, const float* __restrict__ Br1,
    const float* __restrict__ Wr2, const float* __restrict__ Br2,
    const float* __restrict__ Wr3, const float* __restrict__ Br3,
    const float* __restrict__ w8, const float* __restrict__ b8,
    const float* __restrict__ w9, const float* __restrict__ b9,
    h4* __restrict__ tab)
{
    for (int e = threadIdx.x; e < NMM * 64; e += 256) {
        const int q = e >> 6, l = e & 63;
        const int m = l & 15, kq = l >> 4;
        h4 v;
#pragma unroll
        for (int j = 0; j < 4; ++j) {
            const int k = kq * 4 + j;
            float a = 0.0f;
            if (q == 0) {
                if (m < 10 && k < 3)        a = w0[k * 10 + m];
                else if (m < 10 && k == 3)  a = b0[m];
                else if (m == 10 && k == 3) a = 1.0f;
            } else if (q == 33) {
                if (m == 0 && k < 10)       a = w9[k];
                else if (m == 0 && k == 10) a = b9[0];
            } else {
                const float* W = nullptr;
                float bias = 0.0f;
                bool hasB = true, pass = true;
                if (q == 1)       { W = w1; bias = (m < 10) ? b1[m] : 0.0f; }
                else if (q == 32) { W = w8; bias = (m < 10) ? b8[m] : 0.0f; }
                else {
                    const int qq = q - 2, bl = qq / 3, r = qq % 3;
                    if (r == 0)      { W = Wr1 + bl * 100; bias = (m < 10) ? Br1[bl * 10 + m] : 0.0f; }
                    else if (r == 1) { W = Wr2 + bl * 100; bias = (m < 10) ? Br2[bl * 10 + m] + Br3[bl * 10 + m] : 0.0f; }
                    else             { W = Wr3 + bl * 100; hasB = false; pass = false; }
                }
                if (m < 10 && k < 10)                a = W[k * 10 + m];
                else if (m < 10 && k == 10 && hasB)  a = bias;
                else if (m == 10 && k == 10 && pass) a = 1.0f;
            }
            v[j] = (_Float16)a;
        }
        tab[e] = v;
    }
}

// ---------------- main kernel: MFMA layer chain, 4 tile-chains ---------------
__global__ __launch_bounds__(256, 4) void resnet_fwd(
    const float* __restrict__ x,
    const h4* __restrict__ tab,
    float* __restrict__ out)
{
    const int lane = threadIdx.x & 63;
    const int wg = blockIdx.x * 4 + (threadIdx.x >> 6);
    const bool lo = lane < 16;

    // preload all weight fragments (per-lane addresses, one-time)
    h4 wA[NMM];
#pragma unroll
    for (int q = 0; q < NMM; ++q) wA[q] = tab[q * 64 + lane];

    const v4f zero = {0.0f, 0.0f, 0.0f, 0.0f};
    const long tile0 = (long)wg * TPW;

    for (int t = 0; t < TPW; t += ILP) {
        long base[ILP];
        h4 hh[ILP];

        // layer-0 B fragments: quad0 lanes carry (x0,x1,x2,1), others 0
#pragma unroll
        for (int c = 0; c < ILP; ++c) {
            base[c] = (tile0 + t + c) * 16;
            float a0 = 0, a1 = 0, a2 = 0;
            if (lo) {
                const float* p = x + (base[c] + lane) * 3;
                a0 = p[0]; a1 = p[1]; a2 = p[2];
            }
            h4 bx;
            bx[0] = (_Float16)a0; bx[1] = (_Float16)a1; bx[2] = (_Float16)a2;
            bx[3] = lo ? (_Float16)1.0f : (_Float16)0.0f;
            hh[c] = bx;
        }

        // layer 0, layer 1
#pragma unroll
        for (int c = 0; c < ILP; ++c) hh[c] = relu_cvt(mm(wA[0], hh[c], zero));
#pragma unroll
        for (int c = 0; c < ILP; ++c) hh[c] = relu_cvt(mm(wA[1], hh[c], zero));

        // residual blocks (unrolled: wA indices constant)
#pragma unroll
        for (int bl = 0; bl < 10; ++bl) {
            v4f d1[ILP], d2[ILP];
#pragma unroll
            for (int c = 0; c < ILP; ++c) d1[c] = mm(wA[2 + 3 * bl], hh[c], zero);
#pragma unroll
            for (int c = 0; c < ILP; ++c) d2[c] = mm(wA[3 + 3 * bl], hh[c], zero);
#pragma unroll
            for (int c = 0; c < ILP; ++c) {
                h4 t1 = relu_cvt(d1[c]);
                d2[c] = mm(wA[4 + 3 * bl], t1, d2[c]);
            }
#pragma unroll
            for (int c = 0; c < ILP; ++c) hh[c] = relu_cvt(d2[c]);
        }

        // layer 8
#pragma unroll
        for (int c = 0; c < ILP; ++c) hh[c] = relu_cvt(mm(wA[32], hh[c], zero));

        // output layer: row 0 of D = result for the 16 points
#pragma unroll
        for (int c = 0; c < ILP; ++c) {
            v4f d = mm(wA[33], hh[c], zero);
            if (lo) out[base[c] + lane] = d[0];
        }
    }
}

extern "C" void kernel_launch(void* const* d_in, const int* in_sizes, int n_in,
                              void* d_out, int out_size, void* d_ws, size_t ws_size,
                              hipStream_t stream)
{
    const float* x   = (const float*)d_in[0];
    const float* w0  = (const float*)d_in[1];
    const float* b0  = (const float*)d_in[2];
    const float* w1  = (const float*)d_in[3];
    const float* b1  = (const float*)d_in[4];
    const float* Wr1 = (const float*)d_in[5];
    const float* Br1 = (const float*)d_in[6];
    const float* Wr2 = (const float*)d_in[7];
    const float* Br2 = (const float*)d_in[8];
    const float* Wr3 = (const float*)d_in[9];
    const float* Br3 = (const float*)d_in[10];
    const float* w8  = (const float*)d_in[11];
    const float* b8  = (const float*)d_in[12];
    const float* w9  = (const float*)d_in[13];
    const float* b9  = (const float*)d_in[14];
    float* out = (float*)d_out;
    h4* tab = (h4*)d_ws;   // 34 * 64 * 8B = 17.4 KB scratch

    hipLaunchKernelGGL(prepack, dim3(1), dim3(256), 0, stream,
                       w0, b0, w1, b1, Wr1, Br1, Wr2, Br2, Wr3, Br3,
                       w8, b8, w9, b9, tab);

    hipLaunchKernelGGL(resnet_fwd, dim3(NBLK), dim3(256), 0, stream,
                       x, (const h4*)tab, out);
}